// Round 5
// baseline (399.006 us; speedup 1.0000x reference)
//
#include <hip/hip_runtime.h>
#include <hip/hip_bf16.h>

#define NN 50000
#define EE 800000
#define SCAN_B 196   // ceil(NN/256)

typedef unsigned int uint;
typedef unsigned short ushort;
typedef __attribute__((ext_vector_type(8))) short s16x8;
typedef __attribute__((ext_vector_type(4))) float f32x4;

__device__ __forceinline__ float lrelu(float x, float s){ return fmaxf(x, x * s); }

__device__ __forceinline__ ushort bf16_rne(float x){
  uint u = __float_as_uint(x);
  return (ushort)((u + 0x7FFFu + ((u >> 16) & 1u)) >> 16);
}
__device__ __forceinline__ float bf16f(ushort h){ return __uint_as_float(((uint)h) << 16); }

// 16-lane all-reduce sum via DPP (pure VALU, no LDS).
__device__ __forceinline__ float dpp_add16(float x){
  int v = __float_as_int(x), t;
  t = __builtin_amdgcn_update_dpp(0, v, 0xB1, 0xF, 0xF, true);   // quad_perm [1,0,3,2]
  v = __float_as_int(__int_as_float(v) + __int_as_float(t));
  t = __builtin_amdgcn_update_dpp(0, v, 0x4E, 0xF, 0xF, true);   // quad_perm [2,3,0,1]
  v = __float_as_int(__int_as_float(v) + __int_as_float(t));
  t = __builtin_amdgcn_update_dpp(0, v, 0x141, 0xF, 0xF, true);  // row_half_mirror
  v = __float_as_int(__int_as_float(v) + __int_as_float(t));
  t = __builtin_amdgcn_update_dpp(0, v, 0x140, 0xF, 0xF, true);  // row_mirror
  v = __float_as_int(__int_as_float(v) + __int_as_float(t));
  return __int_as_float(v);
}

// ---------------- CSR build ----------------

__global__ void detect_kernel(const int* __restrict__ ei, int* __restrict__ flag){
  __shared__ int any;
  if (threadIdx.x == 0) any = 0;
  __syncthreads();
  if (ei[2 * threadIdx.x + 1] != 0) atomicOr(&any, 1);
  __syncthreads();
  if (threadIdx.x == 0) *flag = (any == 0) ? 1 : 0;
}

__global__ void zero1_kernel(int* __restrict__ a, int n){
  int i = blockIdx.x * blockDim.x + threadIdx.x;
  if (i < n) a[i] = 0;
}

__global__ void count_kernel(const int* __restrict__ ei, const int* __restrict__ flag,
                             int* __restrict__ deg){
  int e = blockIdx.x * blockDim.x + threadIdx.x;
  if (e >= EE) return;
  int d;
  if (*flag){
    const long long* eil = (const long long*)ei;
    d = (int)eil[EE + e];
  } else {
    d = ei[EE + e];
  }
  atomicAdd(&deg[d], 1);
}

__global__ void scan1_kernel(const int* __restrict__ deg, int* __restrict__ rowptr,
                             int* __restrict__ bsum){
  __shared__ int tmp[256];
  int tid = threadIdx.x;
  int idx = blockIdx.x * 256 + tid;
  int v = (idx < NN) ? deg[idx] : 0;
  tmp[tid] = v;
  __syncthreads();
  for (int off = 1; off < 256; off <<= 1){
    int t = (tid >= off) ? tmp[tid - off] : 0;
    __syncthreads();
    tmp[tid] += t;
    __syncthreads();
  }
  if (idx < NN) rowptr[idx] = tmp[tid] - v;
  if (tid == 255) bsum[blockIdx.x] = tmp[255];
}

__global__ void scan2_kernel(const int* __restrict__ bsum, int* __restrict__ boff,
                             int* __restrict__ rowptr){
  __shared__ int tmp[256];
  int tid = threadIdx.x;
  int v = (tid < SCAN_B) ? bsum[tid] : 0;
  tmp[tid] = v;
  __syncthreads();
  for (int off = 1; off < 256; off <<= 1){
    int t = (tid >= off) ? tmp[tid - off] : 0;
    __syncthreads();
    tmp[tid] += t;
    __syncthreads();
  }
  if (tid < SCAN_B) boff[tid] = tmp[tid] - v;
  if (tid == 255) rowptr[NN] = tmp[255];
}

__global__ void scan3_kernel(int* __restrict__ rowptr, const int* __restrict__ boff,
                             int* __restrict__ deg){
  int i = blockIdx.x * 256 + threadIdx.x;
  if (i < NN){ rowptr[i] += boff[blockIdx.x]; deg[i] = 0; }   // deg reused as cursor
}

__global__ void scatter_kernel(const int* __restrict__ ei, const int* __restrict__ flag,
                               const int* __restrict__ rowptr, int* __restrict__ cursor,
                               int* __restrict__ csr_src){
  int e = blockIdx.x * blockDim.x + threadIdx.x;
  if (e >= EE) return;
  int s, d;
  if (*flag){
    const long long* eil = (const long long*)ei;
    s = (int)eil[e];
    d = (int)eil[EE + e];
  } else {
    s = ei[e];
    d = ei[EE + e];
  }
  int pos = atomicAdd(&cursor[d], 1);
  csr_src[rowptr[d] + pos] = s;
}

// ---------------- W prep: transpose + bf16 hi/lo split ----------------
// wt layout (ushort units): per W j: [offu[j] .. +K*C) = hi[c][k], [+K*C .. +2*K*C) = lo[c][k]
__global__ void prep_w_kernel(const float* __restrict__ w0, const float* __restrict__ w1,
                              const float* __restrict__ w2, const float* __restrict__ w3,
                              const float* __restrict__ w4, const float* __restrict__ w5,
                              ushort* __restrict__ wt){
  int gid = blockIdx.x * 256 + threadIdx.x;
  if (gid >= 81920) return;
  const int KK[6]    = {64, 128, 128, 128, 128, 128};
  const int CC[6]    = {128, 128, 128, 128, 128, 64};
  const int cumel[7] = {0, 8192, 24576, 40960, 57344, 73728, 81920};
  const int offu[6]  = {0, 16384, 49152, 81920, 114688, 147456};
  int j = 0;
  while (gid >= cumel[j + 1]) j++;
  int local = gid - cumel[j];
  int K = KK[j], C = CC[j];
  int k = local / C, c = local % C;
  const float* src = (j == 0) ? w0 : (j == 1) ? w1 : (j == 2) ? w2 : (j == 3) ? w3 : (j == 4) ? w4 : w5;
  float v = src[local];
  ushort h = bf16_rne(v);
  float res = v - bf16f(h);
  ushort l = bf16_rne(res);
  wt[offu[j] + c * K + k] = h;
  wt[offu[j] + K * C + c * K + k] = l;
}

// ---------------- MFMA GEMM (bf16x3 split = f32-accurate) ----------------
// Tile: 64 rows x NOUT cols, 256 threads (4 waves x 16 rows). K single-pass.
// A staged in LDS as bf16 hi/lo with XOR swizzle (byte ^= (row&7)<<4).
// W read as pre-transposed bf16 [c][k] frags from global (L2-resident).
// mfma(a,b,acc): D[i][j] = sum_k a[i][k]*b[j][k]; a rows = A rows, b rows = W cols.
// EPI: 0 = +bias (f32 out); 1 = +bias,BN,leaky(0.1); 2 = +bias,leaky(0.1).
// DUAL: phase1 -> OUTH (ushort bf16 messages, +bias), phase2 (Wth2) -> OUTF f32 +bias2.
template<int KIN, int NOUT, int EPI, bool DUAL>
__launch_bounds__(256)
__global__ void mfma_gemm_kernel(const float* __restrict__ A,
                                 const ushort* __restrict__ Wth, const ushort* __restrict__ Wtl,
                                 const float* __restrict__ bias,
                                 const ushort* __restrict__ Wth2, const ushort* __restrict__ Wtl2,
                                 const float* __restrict__ bias2,
                                 const float* __restrict__ bn_g, const float* __restrict__ bn_b,
                                 const float* __restrict__ bn_m, const float* __restrict__ bn_v,
                                 ushort* __restrict__ OUTH, float* __restrict__ OUTF, int n){
  constexpr int KF = KIN / 32;
  constexpr int NF = NOUT / 16;
  __shared__ ushort sAh[64 * KIN];
  __shared__ ushort sAl[64 * KIN];
  const int tid = threadIdx.x;
  const int r0 = blockIdx.x * 64;

  // stage A tile -> bf16 hi/lo, swizzled
  for (int idx = tid; idx < 64 * (KIN / 4); idx += 256){
    int r  = idx / (KIN / 4);
    int k4 = (idx % (KIN / 4)) * 4;
    float4 a = make_float4(0.f, 0.f, 0.f, 0.f);
    if (r0 + r < n) a = *reinterpret_cast<const float4*>(A + (size_t)(r0 + r) * KIN + k4);
    float f[4] = {a.x, a.y, a.z, a.w};
    uint hh[4], ll[4];
    #pragma unroll
    for (int jj = 0; jj < 4; jj++){
      ushort h = bf16_rne(f[jj]);
      float res = f[jj] - bf16f(h);
      hh[jj] = h;
      ll[jj] = bf16_rne(res);
    }
    uint off = ((uint)(r * KIN + k4) * 2u) ^ (uint)((r & 7) << 4);
    *reinterpret_cast<uint2*>((char*)sAh + off) = make_uint2(hh[0] | (hh[1] << 16), hh[2] | (hh[3] << 16));
    *reinterpret_cast<uint2*>((char*)sAl + off) = make_uint2(ll[0] | (ll[1] << 16), ll[2] | (ll[3] << 16));
  }
  __syncthreads();

  const int wave = tid >> 6, lane = tid & 63;
  const int wr = wave * 16;        // wave's row base in tile
  const int fr = lane & 15;        // A-row / W-col within fragment
  const int kg = lane >> 4;        // k-group (k offset kg*8)

  s16x8 ah[KF], al[KF];
  const int arow = wr + fr;
  #pragma unroll
  for (int kf = 0; kf < KF; kf++){
    uint off = ((uint)((arow * KIN + kf * 32 + kg * 8) * 2)) ^ (uint)((arow & 7) << 4);
    ah[kf] = *reinterpret_cast<const s16x8*>((const char*)sAh + off);
    al[kf] = *reinterpret_cast<const s16x8*>((const char*)sAl + off);
  }

  f32x4 acc[NF];
  #pragma unroll
  for (int nf = 0; nf < NF; nf++) acc[nf] = (f32x4){0.f, 0.f, 0.f, 0.f};

  #pragma unroll 2
  for (int nf = 0; nf < NF; nf++){
    int c = nf * 16 + fr;
    const s16x8* wph = reinterpret_cast<const s16x8*>(Wth + (size_t)c * KIN);
    const s16x8* wpl = reinterpret_cast<const s16x8*>(Wtl + (size_t)c * KIN);
    #pragma unroll
    for (int kf = 0; kf < KF; kf++){
      s16x8 wh = wph[kf * 4 + kg];
      s16x8 wl = wpl[kf * 4 + kg];
      acc[nf] = __builtin_amdgcn_mfma_f32_16x16x32_bf16(ah[kf], wh, acc[nf], 0, 0, 0);
      acc[nf] = __builtin_amdgcn_mfma_f32_16x16x32_bf16(al[kf], wh, acc[nf], 0, 0, 0);
      acc[nf] = __builtin_amdgcn_mfma_f32_16x16x32_bf16(ah[kf], wl, acc[nf], 0, 0, 0);
    }
  }

  // epilogue phase 1
  #pragma unroll
  for (int nf = 0; nf < NF; nf++){
    int c = nf * 16 + fr;
    float bb = bias[c];
    float g_ = 0.f, b_ = 0.f, m_ = 0.f, v_ = 0.f;
    if (EPI == 1){ g_ = bn_g[c]; b_ = bn_b[c]; m_ = bn_m[c]; v_ = bn_v[c]; }
    #pragma unroll
    for (int i = 0; i < 4; i++){
      int gr = r0 + wr + kg * 4 + i;
      if (gr < n){
        float v = acc[nf][i] + bb;
        if (EPI == 1){
          v = (v - m_) * rsqrtf(v_ + 1e-5f) * g_ + b_;
          v = lrelu(v, 0.1f);
        }
        if (EPI == 2){ v = lrelu(v, 0.1f); }
        if (DUAL) OUTH[(size_t)gr * NOUT + c] = bf16_rne(v);
        else      OUTF[(size_t)gr * NOUT + c] = v;
      }
    }
  }

  if (DUAL){
    #pragma unroll
    for (int nf = 0; nf < NF; nf++) acc[nf] = (f32x4){0.f, 0.f, 0.f, 0.f};
    #pragma unroll 2
    for (int nf = 0; nf < NF; nf++){
      int c = nf * 16 + fr;
      const s16x8* wph = reinterpret_cast<const s16x8*>(Wth2 + (size_t)c * KIN);
      const s16x8* wpl = reinterpret_cast<const s16x8*>(Wtl2 + (size_t)c * KIN);
      #pragma unroll
      for (int kf = 0; kf < KF; kf++){
        s16x8 wh = wph[kf * 4 + kg];
        s16x8 wl = wpl[kf * 4 + kg];
        acc[nf] = __builtin_amdgcn_mfma_f32_16x16x32_bf16(ah[kf], wh, acc[nf], 0, 0, 0);
        acc[nf] = __builtin_amdgcn_mfma_f32_16x16x32_bf16(al[kf], wh, acc[nf], 0, 0, 0);
        acc[nf] = __builtin_amdgcn_mfma_f32_16x16x32_bf16(ah[kf], wl, acc[nf], 0, 0, 0);
      }
    }
    #pragma unroll
    for (int nf = 0; nf < NF; nf++){
      int c = nf * 16 + fr;
      float bb = bias2[c];
      #pragma unroll
      for (int i = 0; i < 4; i++){
        int gr = r0 + wr + kg * 4 + i;
        if (gr < n) OUTF[(size_t)gr * NOUT + c] = acc[nf][i] + bb;
      }
    }
  }
}

// ---------------- GATv2 edge phase (bf16 messages, predicated batch-8) ----------------
__global__ void gat_edge_kernel(const uint* __restrict__ XLh, const float* __restrict__ XR,
                                const float* __restrict__ att, const float* __restrict__ bias,
                                const float* __restrict__ bn_g, const float* __restrict__ bn_b,
                                const float* __restrict__ bn_m, const float* __restrict__ bn_v,
                                const float* __restrict__ H, float* __restrict__ OUT,
                                const int* __restrict__ rowptr, const int* __restrict__ csr_src,
                                int n){
  int wid  = (int)((blockIdx.x * blockDim.x + threadIdx.x) >> 6);
  int lane = threadIdx.x & 63;
  if (wid >= n) return;
  const int d = wid;
  const int ch = ((lane >> 4) << 4) + (lane & 15);   // uint index in 64-uint row
  const int cb = ch << 1;                            // float channel base
  const float2 a2 = *reinterpret_cast<const float2*>(att + cb);
  const float2 xr = *reinterpret_cast<const float2*>(XR + (long)d * 128 + cb);
  uint ud = XLh[(long)d * 64 + ch];
  const float xd0 = __uint_as_float(ud << 16);
  const float xd1 = __uint_as_float(ud & 0xFFFF0000u);

  float m = dpp_add16(fmaf(a2.x, lrelu(xr.x + xd0, 0.2f), a2.y * lrelu(xr.y + xd1, 0.2f)));
  float den = 1.f;
  float O0 = xd0, O1 = xd1;

  const int start = rowptr[d], end = rowptr[d + 1];
  const int nb = (end - start + 7) >> 3;
  int eb = start;

  uint nxt[8];
  if (nb > 0){
    #pragma unroll
    for (int i = 0; i < 8; i++){
      int ec = eb + i; ec = ec < end ? ec : end - 1;
      nxt[i] = XLh[(long)csr_src[ec] * 64 + ch];
    }
  }
  for (int b = 0; b < nb; b++){
    uint cur[8];
    #pragma unroll
    for (int i = 0; i < 8; i++) cur[i] = nxt[i];
    if (b + 1 < nb){
      int ebn = eb + 8;
      #pragma unroll
      for (int i = 0; i < 8; i++){
        int ec = ebn + i; ec = ec < end ? ec : end - 1;
        nxt[i] = XLh[(long)csr_src[ec] * 64 + ch];
      }
    }
    float f0[8], f1[8], l[8];
    #pragma unroll
    for (int i = 0; i < 8; i++){
      f0[i] = __uint_as_float(cur[i] << 16);
      f1[i] = __uint_as_float(cur[i] & 0xFFFF0000u);
      float t = fmaf(a2.x, lrelu(xr.x + f0[i], 0.2f), a2.y * lrelu(xr.y + f1[i], 0.2f));
      float li = dpp_add16(t);
      l[i] = (eb + i < end) ? li : -1e30f;
    }
    float bm = fmaxf(fmaxf(fmaxf(l[0], l[1]), fmaxf(l[2], l[3])),
                     fmaxf(fmaxf(l[4], l[5]), fmaxf(l[6], l[7])));
    float nm = fmaxf(m, bm);
    float sc = __expf(m - nm);
    float ws = 0.f, ox = 0.f, oy = 0.f;
    #pragma unroll
    for (int i = 0; i < 8; i++){
      float w = __expf(l[i] - nm);
      ws += w;
      ox = fmaf(w, f0[i], ox);
      oy = fmaf(w, f1[i], oy);
    }
    den = fmaf(den, sc, ws);
    O0  = fmaf(O0, sc, ox);
    O1  = fmaf(O1, sc, oy);
    m = nm;
    eb += 8;
  }

  float inv = 1.f / (den + 1e-16f);
  float v0 = O0 * inv + bias[cb];
  float v1 = O1 * inv + bias[cb + 1];
  v0 = (v0 - bn_m[cb])     * rsqrtf(bn_v[cb]     + 1e-5f) * bn_g[cb]     + bn_b[cb];
  v1 = (v1 - bn_m[cb + 1]) * rsqrtf(bn_v[cb + 1] + 1e-5f) * bn_g[cb + 1] + bn_b[cb + 1];
  const float2 h2 = *reinterpret_cast<const float2*>(H + (long)d * 128 + cb);
  float2 res;
  res.x = lrelu(v0, 0.1f) + h2.x;
  res.y = lrelu(v1, 0.1f) + h2.y;
  *reinterpret_cast<float2*>(OUT + (long)d * 128 + cb) = res;
}

// ---------------- final 64->1 projection ----------------
__global__ void out2_kernel(const float* __restrict__ Hin, const float* __restrict__ Wo2,
                            const float* __restrict__ bo2, float* __restrict__ out, int n){
  int wid  = (int)((blockIdx.x * blockDim.x + threadIdx.x) >> 6);
  int lane = threadIdx.x & 63;
  if (wid >= n) return;
  float p = Hin[(long)wid * 64 + lane] * Wo2[lane];
  #pragma unroll
  for (int off = 1; off < 64; off <<= 1) p += __shfl_xor(p, off);
  if (lane == 0) out[wid] = p + bo2[0];
}

// ---------------- launch ----------------
extern "C" void kernel_launch(void* const* d_in, const int* in_sizes, int n_in,
                              void* d_out, int out_size, void* d_ws, size_t ws_size,
                              hipStream_t stream) {
  const float* x     = (const float*)d_in[0];
  const int*   ei    = (const int*)  d_in[1];
  const float* W_pre = (const float*)d_in[2];
  const float* b_pre = (const float*)d_in[3];
  const float* g_pre = (const float*)d_in[4];
  const float* be_pre= (const float*)d_in[5];
  const float* m_pre = (const float*)d_in[6];
  const float* v_pre = (const float*)d_in[7];
  const float* Wl1  = (const float*)d_in[8];
  const float* bl1  = (const float*)d_in[9];
  const float* Wr1  = (const float*)d_in[10];
  const float* br1  = (const float*)d_in[11];
  const float* att1 = (const float*)d_in[12];
  const float* bias1= (const float*)d_in[13];
  const float* g1   = (const float*)d_in[14];
  const float* be1  = (const float*)d_in[15];
  const float* m1   = (const float*)d_in[16];
  const float* v1   = (const float*)d_in[17];
  const float* Wl2  = (const float*)d_in[18];
  const float* bl2  = (const float*)d_in[19];
  const float* Wr2  = (const float*)d_in[20];
  const float* br2  = (const float*)d_in[21];
  const float* att2 = (const float*)d_in[22];
  const float* bias2= (const float*)d_in[23];
  const float* g2   = (const float*)d_in[24];
  const float* be2  = (const float*)d_in[25];
  const float* m2   = (const float*)d_in[26];
  const float* v2   = (const float*)d_in[27];
  const float* Wo1  = (const float*)d_in[28];
  const float* bo1  = (const float*)d_in[29];
  const float* Wo2  = (const float*)d_in[30];
  const float* bo2  = (const float*)d_in[31];
  float* out = (float*)d_out;
  char*  ws  = (char*)d_ws;

  float*  buf0 = (float*)(ws + 0);           // [N,128] f32
  float*  buf2 = (float*)(ws + 25600000);    // [N,128] f32 (also out1's [N,64])
  uint*   hbuf = (uint*) (ws + 51200000);    // [N,64] packed bf16 pairs (12.8 MB)
  int* rowptr = (int*)(ws + 64000000);       // N+1
  int* deg    = (int*)(ws + 64200448);       // N (reused as scatter cursor)
  int* bsum   = (int*)(ws + 64400448);       // SCAN_B
  int* boff   = (int*)(ws + 64401472);       // SCAN_B
  int* csr    = (int*)(ws + 64600448);       // E (3.2 MB)
  int* flag   = (int*)(ws + 67800448);       // 1
  ushort* wt  = (ushort*)(ws + 68000000);    // 320 KB bf16 hi/lo transposed weights

  const ushort* wtPre_h = wt;                  const ushort* wtPre_l = wt + 8192;
  const ushort* wtL1_h  = wt + 16384;          const ushort* wtL1_l  = wt + 16384 + 16384;
  const ushort* wtR1_h  = wt + 49152;          const ushort* wtR1_l  = wt + 49152 + 16384;
  const ushort* wtL2_h  = wt + 81920;          const ushort* wtL2_l  = wt + 81920 + 16384;
  const ushort* wtR2_h  = wt + 114688;         const ushort* wtR2_l  = wt + 114688 + 16384;
  const ushort* wtO1_h  = wt + 147456;         const ushort* wtO1_l  = wt + 147456 + 8192;

  // CSR build (reused by both GAT layers)
  detect_kernel<<<1, 256, 0, stream>>>(ei, flag);
  zero1_kernel<<<SCAN_B, 256, 0, stream>>>(deg, NN);
  count_kernel<<<(EE + 255) / 256, 256, 0, stream>>>(ei, flag, deg);
  scan1_kernel<<<SCAN_B, 256, 0, stream>>>(deg, rowptr, bsum);
  scan2_kernel<<<1, 256, 0, stream>>>(bsum, boff, rowptr);
  scan3_kernel<<<SCAN_B, 256, 0, stream>>>(rowptr, boff, deg);
  scatter_kernel<<<(EE + 255) / 256, 256, 0, stream>>>(ei, flag, rowptr, deg, csr);

  // weight prep (transpose + bf16 hi/lo)
  prep_w_kernel<<<320, 256, 0, stream>>>(W_pre, Wl1, Wr1, Wl2, Wr2, Wo1, wt);

  const int GB = (NN + 63) / 64;     // 782 MFMA-GEMM blocks
  const int GW = (NN + 3) / 4;       // wave-per-node blocks

  // pre: buf0 = leaky(BN(x@W_pre + b_pre))
  mfma_gemm_kernel<64, 128, 1, false><<<GB, 256, 0, stream>>>(
      x, wtPre_h, wtPre_l, b_pre, nullptr, nullptr, nullptr,
      g_pre, be_pre, m_pre, v_pre, nullptr, buf0, NN);
  // layer 1: hbuf = bf16(buf0@Wl1+bl1), buf2 = buf0@Wr1+br1
  mfma_gemm_kernel<128, 128, 0, true><<<GB, 256, 0, stream>>>(
      buf0, wtL1_h, wtL1_l, bl1, wtR1_h, wtR1_l, br1,
      nullptr, nullptr, nullptr, nullptr, (ushort*)hbuf, buf2, NN);
  gat_edge_kernel<<<GW, 256, 0, stream>>>(hbuf, buf2, att1, bias1, g1, be1, m1, v1,
                                          buf0 /*H*/, buf2 /*OUT in-place*/, rowptr, csr, NN);
  // layer 2: hbuf = bf16(buf2@Wl2+bl2), buf0 = buf2@Wr2+br2
  mfma_gemm_kernel<128, 128, 0, true><<<GB, 256, 0, stream>>>(
      buf2, wtL2_h, wtL2_l, bl2, wtR2_h, wtR2_l, br2,
      nullptr, nullptr, nullptr, nullptr, (ushort*)hbuf, buf0, NN);
  gat_edge_kernel<<<GW, 256, 0, stream>>>(hbuf, buf0, att2, bias2, g2, be2, m2, v2,
                                          buf2 /*H*/, buf0 /*OUT in-place*/, rowptr, csr, NN);
  // out head: buf2[:, :64] = leaky(buf0@Wo1+bo1); out = buf2@Wo2+bo2
  mfma_gemm_kernel<128, 64, 2, false><<<GB, 256, 0, stream>>>(
      buf0, wtO1_h, wtO1_l, bo1, nullptr, nullptr, nullptr,
      nullptr, nullptr, nullptr, nullptr, nullptr, buf2, NN);
  out2_kernel<<<GW, 256, 0, stream>>>(buf2, Wo2, bo2, out, NN);
}